// Round 1
// baseline (920.743 us; speedup 1.0000x reference)
//
#include <hip/hip_runtime.h>

#define NB 128
#define NT 2048
#define NL 128
#define START_LBL 126
#define STOP_LBL 127

typedef float f4 __attribute__((ext_vector_type(4)));

__device__ __forceinline__ float bcast_lane(float v, int l) {
    // wave-uniform broadcast via readlane -> SGPR (folds as scalar operand of v_add_f32)
    return __int_as_float(__builtin_amdgcn_readlane(__float_as_int(v), l));
}

// One block per batch. 8 waves: wave w owns k in [16w, 16w+16); each lane holds
// transition columns j=lane and j=lane+64 in registers (32 VGPRs).
// Per step: partial max over own k-range -> swizzled LDS partials -> single
// barrier -> each wave reduces the 8 partials for the 16 j's it needs as next
// step's v (v never round-trips through a central buffer).
__global__ __launch_bounds__(512, 2) void crf_viterbi(
    const float* __restrict__ em, const float* __restrict__ tr,
    float* __restrict__ out)
{
    const int b    = blockIdx.x;
    const int tid  = threadIdx.x;
    const int w    = tid >> 6;          // wave 0..7
    const int lane = tid & 63;
    const int j0   = lane;
    const int j1   = lane + 64;
    const int kbase = w << 4;           // this wave's k-range base
    const int l15  = lane & 15;
    const int jj   = kbase + l15;       // the j this lane finalizes (4-way dup)

    __shared__ __align__(16) float part[2][NL][12];   // [buf][j][col(+pad)]
    __shared__ __align__(16) float elds[2][32][NL];   // emission chunks (32 steps)
    __shared__ float vfin[NL];

    // ---- load transition columns into registers (coalesced: lane-consecutive j)
    float trA[16], trB[16];
#pragma unroll
    for (int kk = 0; kk < 16; ++kk) {
        trA[kk] = tr[(kbase + kk) * NL + j0];
        trB[kk] = tr[(kbase + kk) * NL + j1];
    }

    const float* eb = em + (size_t)b * NT * NL;

    // ---- preload emission chunk 0 (rows 0..31) via async global->LDS, width 16
    {
        const float* src = eb + tid * 4;
        float* dst = &elds[0][0][0] + tid * 4;
        __builtin_amdgcn_global_load_lds(
            (const __attribute__((address_space(1))) void*)src,
            (__attribute__((address_space(3))) void*)dst, 16, 0, 0);
        __builtin_amdgcn_global_load_lds(
            (const __attribute__((address_space(1))) void*)(src + 2048),
            (__attribute__((address_space(3))) void*)(dst + 2048), 16, 0, 0);
    }
    asm volatile("s_waitcnt vmcnt(0)" ::: "memory");
    __syncthreads();

    // ---- v0: -10000 except START label = 0 (emissions[:,0] NOT added)
    float vv = (jj == START_LBL) ? 0.0f : -10000.0f;

    // partial-write column rotation: bank-conflict-breaking, bijective per row,
    // reader max-reduces all 8 columns so no de-swizzle needed
    const int col = (w + (lane >> 3)) & 7;

#pragma unroll 2
    for (int t = 1; t < NT; ++t) {
        const int pb = t & 1;

        // issue next emission chunk one iteration after the chunk-entry barrier
        // (all waves provably done reading the buffer being overwritten)
        if ((t & 31) == 1 && t < NT - 32) {
            const int tcn = (t >> 5) + 1;
            const float* src = eb + (size_t)tcn * 32 * NL + tid * 4;
            float* dst = &elds[tcn & 1][0][0] + tid * 4;
            __builtin_amdgcn_global_load_lds(
                (const __attribute__((address_space(1))) void*)src,
                (__attribute__((address_space(3))) void*)dst, 16, 0, 0);
            __builtin_amdgcn_global_load_lds(
                (const __attribute__((address_space(1))) void*)(src + 2048),
                (__attribute__((address_space(3))) void*)(dst + 2048), 16, 0, 0);
        }
        // drain chunk loads only at chunk boundaries (31 iters of flight time)
        if ((t & 31) == 0) {
            asm volatile("s_waitcnt vmcnt(0)" ::: "memory");
        }

        // ---- inner: partial max over this wave's 16 k's for both j columns
        float a0 = -3.0e38f, a1 = -3.0e38f;
#pragma unroll
        for (int kk = 0; kk < 16; kk += 2) {
            float vb0 = bcast_lane(vv, kk);
            float vb1 = bcast_lane(vv, kk + 1);
            float x0 = vb0 + trA[kk];
            float x1 = vb1 + trA[kk + 1];
            a0 = fmaxf(fmaxf(a0, x0), x1);   // -> v_max3_f32
            float y0 = vb0 + trB[kk];
            float y1 = vb1 + trB[kk + 1];
            a1 = fmaxf(fmaxf(a1, y0), y1);
        }

        part[pb][j0][col] = a0;
        part[pb][j1][col] = a1;
        __syncthreads();                      // ONE barrier/step (part dbl-buffered)

        // ---- finalize: reduce 8 partials for this lane's jj, add emission
        f4 pa = *(const f4*)&part[pb][jj][0];
        f4 pc = *(const f4*)&part[pb][jj][4];
        float e = elds[(t >> 5) & 1][t & 31][jj];
        float m = fmaxf(fmaxf(pa.x, pa.y), pa.z);
        m = fmaxf(fmaxf(m, pa.w), pc.x);
        m = fmaxf(fmaxf(m, pc.y), pc.z);
        m = fmaxf(m, pc.w);
        vv = m + e;                           // v_new[jj] — exactly next step's input
    }

    // ---- epilogue: + transitions[:, STOP], then block argmax (first-index wins)
    float vf = vv + tr[jj * NL + STOP_LBL];
    if (lane < 16) vfin[jj] = vf;
    __syncthreads();

    if (tid < 64) {
        float v0 = vfin[tid];
        float v1 = vfin[tid + 64];
        float val; int idx;
        if (v1 > v0) { val = v1; idx = tid + 64; } else { val = v0; idx = tid; }
#pragma unroll
        for (int off = 32; off >= 1; off >>= 1) {
            float ov = __shfl_xor(val, off, 64);
            int   oi = __shfl_xor(idx, off, 64);
            if (ov > val || (ov == val && oi < idx)) { val = ov; idx = oi; }
        }
        if (tid == 0) {
            out[b]      = val;           // best_final_score
            out[NB + b] = (float)idx;    // best_final_label (float-encoded)
        }
    }
}

extern "C" void kernel_launch(void* const* d_in, const int* in_sizes, int n_in,
                              void* d_out, int out_size, void* d_ws, size_t ws_size,
                              hipStream_t stream) {
    const float* em = (const float*)d_in[0];   // [128, 2048, 128] f32
    const float* tr = (const float*)d_in[1];   // [128, 128] f32
    float* out = (float*)d_out;                // [128] scores ++ [128] labels
    crf_viterbi<<<NB, 512, 0, stream>>>(em, tr, out);
}

// Round 3
// 914.702 us; speedup vs baseline: 1.0066x; 1.0066x over previous
//
#include <hip/hip_runtime.h>

#define NB 128
#define NT 2048
#define NL 128
#define START_LBL 126
#define STOP_LBL 127

typedef float f4 __attribute__((ext_vector_type(4)));

__device__ __forceinline__ float bcast_lane(float v, int l) {
    // wave-uniform broadcast via readlane -> SGPR (folds as scalar operand of v_add_f32)
    return __int_as_float(__builtin_amdgcn_readlane(__float_as_int(v), l));
}

// One block per batch. 8 waves: wave w owns k in [16w, 16w+16); each lane holds
// transition columns j=lane and j=lane+64 in registers (32 VGPRs).
// Per step: partial max over own k-range -> swizzled LDS partials -> ONE barrier
// -> each wave reduces the 8 partials for the 16 j's it needs as next step's v.
//
// Barrier discipline: raw {s_waitcnt lgkmcnt(0); s_barrier} on 31/32 steps so
// the async emission-chunk global_load_lds stays in flight across barriers;
// full __syncthreads() (drains vmcnt for every wave) only at t%32==31, right
// before any wave reads the freshly loaded chunk.
__global__ __launch_bounds__(512, 2) void crf_viterbi(
    const float* __restrict__ em, const float* __restrict__ tr,
    float* __restrict__ out)
{
    const int b    = blockIdx.x;
    const int tid  = threadIdx.x;
    const int w    = tid >> 6;          // wave 0..7
    const int lane = tid & 63;
    const int j0   = lane;
    const int j1   = lane + 64;
    const int kbase = w << 4;           // this wave's k-range base
    const int l15  = lane & 15;
    const int jj   = kbase + l15;       // the j this lane finalizes (4-way dup)

    __shared__ __align__(16) float part[2][NL][12];   // [buf][j][col(+pad)]
    __shared__ __align__(16) float elds[2][32][NL];   // emission chunks (32 steps)
    __shared__ float vfin[NL];

    // ---- load transition columns into registers (coalesced: lane-consecutive j)
    float trA[16], trB[16];
#pragma unroll
    for (int kk = 0; kk < 16; ++kk) {
        trA[kk] = tr[(kbase + kk) * NL + j0];
        trB[kk] = tr[(kbase + kk) * NL + j1];
    }

    const float* eb = em + (size_t)b * NT * NL;

    // ---- preload emission chunk 0 (rows 0..31) via async global->LDS, width 16
    {
        const float* src = eb + tid * 4;
        float* dst = &elds[0][0][0] + tid * 4;
        __builtin_amdgcn_global_load_lds(
            (const __attribute__((address_space(1))) void*)src,
            (__attribute__((address_space(3))) void*)dst, 16, 0, 0);
        __builtin_amdgcn_global_load_lds(
            (const __attribute__((address_space(1))) void*)(src + 2048),
            (__attribute__((address_space(3))) void*)(dst + 2048), 16, 0, 0);
    }
    __syncthreads();   // drains vmcnt(0): chunk 0 resident for all waves

    // ---- v0: -10000 except START label = 0 (emissions[:,0] NOT added)
    float vv = (jj == START_LBL) ? 0.0f : -10000.0f;

    // partial-write column rotation: bank-conflict-breaking, bijective per row,
    // reader max-reduces all 8 columns so no de-swizzle needed
    const int col = (w + (lane >> 3)) & 7;

#pragma unroll 2
    for (int t = 1; t < NT; ++t) {
        const int pb = t & 1;

        // ---- emission read issued EARLY: depends only on t (chunk resident
        // since the t%32==31 __syncthreads), latency hides under inner loop
        float e = elds[(t >> 5) & 1][t & 31][jj];

        // issue next emission chunk one iteration after the chunk-entry point
        // (all waves provably done reading the buffer being overwritten)
        if ((t & 31) == 1 && t < NT - 32) {
            const int tcn = (t >> 5) + 1;
            const float* src = eb + (size_t)tcn * 32 * NL + tid * 4;
            float* dst = &elds[tcn & 1][0][0] + tid * 4;
            __builtin_amdgcn_global_load_lds(
                (const __attribute__((address_space(1))) void*)src,
                (__attribute__((address_space(3))) void*)dst, 16, 0, 0);
            __builtin_amdgcn_global_load_lds(
                (const __attribute__((address_space(1))) void*)(src + 2048),
                (__attribute__((address_space(3))) void*)(dst + 2048), 16, 0, 0);
        }

        // ---- batch all 16 broadcasts first (independent; amortizes
        // readlane->SGPR->VALU wait-states instead of paying them per add)
        float vb[16];
#pragma unroll
        for (int kk = 0; kk < 16; ++kk) vb[kk] = bcast_lane(vv, kk);

        // ---- inner: partial max over this wave's 16 k's for both j columns
        float a0 = fmaxf(vb[0] + trA[0], vb[1] + trA[1]);
        float a1 = fmaxf(vb[0] + trB[0], vb[1] + trB[1]);
#pragma unroll
        for (int kk = 2; kk < 16; kk += 2) {
            float x0 = vb[kk]     + trA[kk];
            float x1 = vb[kk + 1] + trA[kk + 1];
            a0 = fmaxf(fmaxf(a0, x0), x1);   // -> v_max3_f32
            float y0 = vb[kk]     + trB[kk];
            float y1 = vb[kk + 1] + trB[kk + 1];
            a1 = fmaxf(fmaxf(a1, y0), y1);
        }

        part[pb][j0][col] = a0;
        part[pb][j1][col] = a1;

        // ---- ONE barrier/step. Raw s_barrier keeps chunk loads in flight;
        // full __syncthreads (vmcnt drain) only right before a chunk switch.
        if ((t & 31) == 31) {
            __syncthreads();
        } else {
            asm volatile("s_waitcnt lgkmcnt(0)\n\ts_barrier" ::: "memory");
        }

        // ---- finalize: reduce 8 partials for this lane's jj, add emission
        f4 pa = *(const f4*)&part[pb][jj][0];
        f4 pc = *(const f4*)&part[pb][jj][4];
        float m = fmaxf(fmaxf(pa.x, pa.y), pa.z);
        m = fmaxf(fmaxf(m, pa.w), pc.x);
        m = fmaxf(fmaxf(m, pc.y), pc.z);
        m = fmaxf(m, pc.w);
        vv = m + e;                           // v_new[jj] — next step's input
    }

    // ---- epilogue: + transitions[:, STOP], then block argmax (first-index wins)
    float vf = vv + tr[jj * NL + STOP_LBL];
    if (lane < 16) vfin[jj] = vf;
    __syncthreads();

    if (tid < 64) {
        float v0 = vfin[tid];
        float v1 = vfin[tid + 64];
        float val; int idx;
        if (v1 > v0) { val = v1; idx = tid + 64; } else { val = v0; idx = tid; }
#pragma unroll
        for (int off = 32; off >= 1; off >>= 1) {
            float ov = __shfl_xor(val, off, 64);
            int   oi = __shfl_xor(idx, off, 64);
            if (ov > val || (ov == val && oi < idx)) { val = ov; idx = oi; }
        }
        if (tid == 0) {
            out[b]      = val;           // best_final_score
            out[NB + b] = (float)idx;    // best_final_label (float-encoded)
        }
    }
}

extern "C" void kernel_launch(void* const* d_in, const int* in_sizes, int n_in,
                              void* d_out, int out_size, void* d_ws, size_t ws_size,
                              hipStream_t stream) {
    const float* em = (const float*)d_in[0];   // [128, 2048, 128] f32
    const float* tr = (const float*)d_in[1];   // [128, 128] f32
    float* out = (float*)d_out;                // [128] scores ++ [128] labels
    crf_viterbi<<<NB, 512, 0, stream>>>(em, tr, out);
}

// Round 7
// 832.790 us; speedup vs baseline: 1.1056x; 1.0984x over previous
//
#include <hip/hip_runtime.h>

#define NB 128
#define NT 2048
#define NL 128
#define START_LBL 126
#define STOP_LBL 127

typedef float f4 __attribute__((ext_vector_type(4)));
typedef float f2 __attribute__((ext_vector_type(2)));

__device__ __forceinline__ float bcast_lane(float v, int l) {
    // wave-uniform broadcast via readlane -> SGPR (folds as scalar operand)
    return __int_as_float(__builtin_amdgcn_readlane(__float_as_int(v), l));
}

// One block per batch, 4 waves (256 thr), 1 wave/SIMD. Wave w owns k in
// [32w, 32w+32); lane holds packed transition pairs (T[k,j0], T[k,j1]) for
// j0=lane, j1=lane+64 -> 64 VGPRs, added via v_pk_add_f32 (1 instr / 2 adds).
// Per step: 32 readlane broadcasts of v (SGPRs) -> 32 pk_add + 32 max3 ->
// swizzled LDS partials [j][4] -> ONE barrier -> each wave ds_read_b128's the
// 4 partials for the 32 j's it owns next step. v never leaves registers/LDS
// partials; emissions double-buffered in LDS via async global_load_lds with
// vmcnt drained only at 1-of-32 chunk-boundary __syncthreads.
__global__ __launch_bounds__(256, 1) void crf_viterbi(
    const float* __restrict__ em, const float* __restrict__ tr,
    float* __restrict__ out)
{
    const int b    = blockIdx.x;
    const int tid  = threadIdx.x;
    const int w    = tid >> 6;          // wave 0..3
    const int lane = tid & 63;
    const int j0   = lane;
    const int j1   = lane + 64;
    const int kbase = w << 5;           // this wave's k-range base (32 k's)
    const int l31  = lane & 31;
    const int jj   = kbase + l31;       // the j this lane finalizes (2-way dup)

    __shared__ __align__(16) float part[2][NL][4];    // [buf][j][wave] 16B rows
    __shared__ __align__(16) float elds[2][32][NL];   // emission chunks
    __shared__ float vfin[NL];

    // ---- packed transition pairs (coalesced: lane-consecutive j)
    f2 t2[32];
#pragma unroll
    for (int kk = 0; kk < 32; ++kk) {
        t2[kk].x = tr[(kbase + kk) * NL + j0];
        t2[kk].y = tr[(kbase + kk) * NL + j1];
    }

    const float* eb = em + (size_t)b * NT * NL;

    // ---- preload emission chunk 0 (16 KB = 4 x 4KB wave-linear loads)
#pragma unroll
    for (int i = 0; i < 4; ++i) {
        const float* src = eb + i * 1024 + tid * 4;
        float* dst = &elds[0][0][0] + i * 1024 + tid * 4;
        __builtin_amdgcn_global_load_lds(
            (const __attribute__((address_space(1))) void*)src,
            (__attribute__((address_space(3))) void*)dst, 16, 0, 0);
    }
    __syncthreads();   // drains vmcnt(0): chunk 0 resident for all waves

    // ---- v0: -10000 except START label = 0 (emissions[:,0] NOT added)
    float vv = (jj == START_LBL) ? 0.0f : -10000.0f;

    // partial-write column rotation (2-way max on write banks = free)
    const int col = (w + (lane >> 4)) & 3;

#pragma unroll 2
    for (int t = 1; t < NT; ++t) {
        const int pb = t & 1;

        // ---- emission read issued EARLY (latency hides under inner issue)
        float e = elds[(t >> 5) & 1][t & 31][jj];

        // issue next emission chunk (31 steps of flight before the drain)
        if ((t & 31) == 1 && t < NT - 32) {
            const int tcn = (t >> 5) + 1;
            const float* srcb = eb + (size_t)tcn * 32 * NL;
            float* dstb = &elds[tcn & 1][0][0];
#pragma unroll
            for (int i = 0; i < 4; ++i) {
                __builtin_amdgcn_global_load_lds(
                    (const __attribute__((address_space(1))) void*)(srcb + i * 1024 + tid * 4),
                    (__attribute__((address_space(3))) void*)(dstb + i * 1024 + tid * 4),
                    16, 0, 0);
            }
        }

        // ---- inner: max over this wave's 32 k's, both j columns packed.
        // 2 alternating accumulator chains per column halve serial max3 depth.
        float a0A = -3.0e38f, a0B = -3.0e38f;
        float a1A = -3.0e38f, a1B = -3.0e38f;
#pragma unroll
        for (int half = 0; half < 2; ++half) {
            // batch 16 broadcasts (independent; live in SGPRs)
            float s[16];
#pragma unroll
            for (int kk = 0; kk < 16; ++kk)
                s[kk] = bcast_lane(vv, half * 16 + kk);
#pragma unroll
            for (int kk = 0; kk < 16; kk += 2) {
                f2 sv0; sv0.x = s[kk];     sv0.y = s[kk];
                f2 sv1; sv1.x = s[kk + 1]; sv1.y = s[kk + 1];
                f2 r0 = t2[half * 16 + kk]     + sv0;   // v_pk_add_f32
                f2 r1 = t2[half * 16 + kk + 1] + sv1;   // v_pk_add_f32
                if ((kk & 2) == 0) {
                    a0A = fmaxf(fmaxf(a0A, r0.x), r1.x);  // v_max3_f32
                    a1A = fmaxf(fmaxf(a1A, r0.y), r1.y);
                } else {
                    a0B = fmaxf(fmaxf(a0B, r0.x), r1.x);
                    a1B = fmaxf(fmaxf(a1B, r0.y), r1.y);
                }
            }
        }
        float a0 = fmaxf(a0A, a0B);
        float a1 = fmaxf(a1A, a1B);

        part[pb][j0][col] = a0;
        part[pb][j1][col] = a1;

        // ---- ONE barrier/step. Raw s_barrier keeps chunk loads in flight;
        // full __syncthreads (vmcnt drain) only right before a chunk switch.
        if ((t & 31) == 31) {
            __syncthreads();
        } else {
            asm volatile("s_waitcnt lgkmcnt(0)\n\ts_barrier" ::: "memory");
        }

        // ---- finalize: reduce the 4 partials for this lane's jj, add emission
        f4 pa = *(const f4*)&part[pb][jj][0];
        float m = fmaxf(fmaxf(pa.x, pa.y), fmaxf(pa.z, pa.w));
        vv = m + e;                           // v_new[jj] — next step's input
    }

    // ---- epilogue: + transitions[:, STOP], then block argmax (first-index wins)
    float vf = vv + tr[jj * NL + STOP_LBL];
    if (lane < 32) vfin[jj] = vf;
    __syncthreads();

    if (tid < 64) {
        float v0 = vfin[tid];
        float v1 = vfin[tid + 64];
        float val; int idx;
        if (v1 > v0) { val = v1; idx = tid + 64; } else { val = v0; idx = tid; }
#pragma unroll
        for (int off = 32; off >= 1; off >>= 1) {
            float ov = __shfl_xor(val, off, 64);
            int   oi = __shfl_xor(idx, off, 64);
            if (ov > val || (ov == val && oi < idx)) { val = ov; idx = oi; }
        }
        if (tid == 0) {
            out[b]      = val;           // best_final_score
            out[NB + b] = (float)idx;    // best_final_label (float-encoded)
        }
    }
}

extern "C" void kernel_launch(void* const* d_in, const int* in_sizes, int n_in,
                              void* d_out, int out_size, void* d_ws, size_t ws_size,
                              hipStream_t stream) {
    const float* em = (const float*)d_in[0];   // [128, 2048, 128] f32
    const float* tr = (const float*)d_in[1];   // [128, 128] f32
    float* out = (float*)d_out;                // [128] scores ++ [128] labels
    crf_viterbi<<<NB, 256, 0, stream>>>(em, tr, out);
}